// Round 1
// baseline (10383.363 us; speedup 1.0000x reference)
//
#include <hip/hip_runtime.h>
#include <cstdint>
#include <cstddef>

typedef __bf16 bf16x8 __attribute__((ext_vector_type(8)));
typedef __bf16 bf16x4 __attribute__((ext_vector_type(4)));
typedef float  f32x4  __attribute__((ext_vector_type(4)));

// ---------------- ws layout (bytes) ----------------
// [0,            12582912)  : W fragments, bf16, 128 slices * 48 ksteps * 2 ntiles * 64 lanes * 8
// [12582912,     29360128)  : data cast to bf16, [32][512][512]
// [29360128,     29491200)  : h double buffer, bf16 [2][32][1024]
// [29491200,     29493248)  : barrier counters (2 groups * 4 lines * 64 uints)
#define WS_WFRAG   0
#define WS_XB      12582912
#define WS_HBUF    29360128
#define WS_CNT     29491200
#define WS_NEEDED  29493248

#define LDS_BYTES  149632   // A: 48*512*2 = 49152 ; W: 96*512*2 = 98304 ; scr: 2*272*4 = 2176

__device__ __forceinline__ void gload16(const void* g, void* l) {
    __builtin_amdgcn_global_load_lds(
        (const __attribute__((address_space(1))) void*)(g),
        (__attribute__((address_space(3))) void*)(l),
        16, 0, 0);
}

__device__ __forceinline__ float sigmoidf_(float x) {
    return 1.f / (1.f + __expf(-x));
}
__device__ __forceinline__ float tanhf_(float x) {
    x = fminf(fmaxf(x, -15.f), 15.f);
    float e2 = __expf(2.f * x);
    return (e2 - 1.f) / (e2 + 1.f);
}

// ---- prep: shuffle fused W = [Wx ; Wh] (K=1536, N=4096 fp32) into bf16 B-fragment order ----
// chunk index tid = ((s*48 + kk)*2 + nt)*64 + l ; each chunk = 8 consecutive k for one column.
// column mapping within slice s: c = nt*16 + (l&15); uu = c>>2 (unit 0..7), gi = c&3 (i,f,g,o);
// global col n = gi*1024 + s*8 + uu.
__global__ void __launch_bounds__(256) prep_w_kernel(const float* __restrict__ Wx,
                                                     const float* __restrict__ Wh,
                                                     __bf16* __restrict__ wfrag) {
    int tid = blockIdx.x * 256 + threadIdx.x;   // 0 .. 786431
    int l   = tid & 63;
    int m   = tid >> 6;        // (s*48+kk)*2+nt
    int nt  = m & 1;
    int sk  = m >> 1;          // s*48+kk
    int kk  = sk % 48;
    int s   = sk / 48;
    int lc  = l & 15;
    int c   = nt * 16 + lc;
    int uu  = c >> 2;
    int gi  = c & 3;
    int n   = gi * 1024 + s * 8 + uu;
    int k0  = kk * 32 + (l >> 4) * 8;
    bf16x8 v;
#pragma unroll
    for (int j = 0; j < 8; ++j) {
        int k  = k0 + j;
        float f = (k < 512) ? Wx[k * 4096 + n] : Wh[(k - 512) * 4096 + n];
        v[j] = (__bf16)f;
    }
    ((bf16x8*)wfrag)[tid] = v;
}

// ---- prep: cast data fp32 -> bf16 (layout preserved [32][512][512]) ----
__global__ void __launch_bounds__(256) prep_x_kernel(const float* __restrict__ data,
                                                     __bf16* __restrict__ xb) {
    int tid = blockIdx.x * 256 + threadIdx.x;   // 0 .. 2097151 (x4 elems)
    float4 v = ((const float4*)data)[tid];
    bf16x4 o;
    o[0] = (__bf16)v.x; o[1] = (__bf16)v.y; o[2] = (__bf16)v.z; o[3] = (__bf16)v.w;
    ((bf16x4*)xb)[tid] = o;
}

// ---- persistent LSTM kernel ----
// grid = 256 blocks x 128 threads. block -> (g = bid>>7, s = bid&127).
// group g = batch rows [16g, 16g+16). slice s = units [8s, 8s+8) (32 gate cols).
// LDS: A (48 ksteps x 64 lanes x 8 bf16), W (96 chunks x 512 bf16), scr (2 x 16x17 f32).
__global__ void __launch_bounds__(128)
lstm_main(const __bf16* __restrict__ xb, const __bf16* __restrict__ wfrag,
          const float* __restrict__ bias, float* __restrict__ out,
          __bf16* __restrict__ hbuf, unsigned* __restrict__ cnt) {
    extern __shared__ char smem[];
    __bf16* A_lds = (__bf16*)smem;                       // 24576 elems
    __bf16* W_lds = (__bf16*)(smem + 49152);             // 49152 elems
    float*  scr   = (float*)(smem + 49152 + 98304);      // 2 * 272 floats

    const int tid = threadIdx.x;
    const int l   = tid & 63;
    const int w   = tid >> 6;        // wave id == N-tile id (0,1)
    const int q   = l >> 4;          // quad id 0..3
    const int r   = l & 15;          // 0..15
    const int bid = blockIdx.x;
    const int s   = bid & 127;
    const int g   = bid >> 7;
    const int gb0 = g * 16;

    // ---- stage W slice into LDS (once), coalesced 16B/lane ----
    const __bf16* wsrc = wfrag + (size_t)s * 49152;
    for (int m = w * 48; m < w * 48 + 48; ++m) {
        gload16(wsrc + m * 512 + l * 8, W_lds + m * 512);
    }

    // ---- per-lane epilogue constants ----
    const int uu = w * 4 + q;            // unit within slice, 0..7
    const int u  = s * 8 + uu;           // global unit
    const float b_i = bias[u];
    const float b_f = bias[1024 + u];
    const float b_g = bias[2048 + u];
    const float b_o = bias[3072 + u];
    float cst = 0.f;                     // cell state for (unit u, batch row gb0+r)

    unsigned* cbase = cnt + g * 256;             // group's 4 counter lines, 64 uints apart
    unsigned* mycnt = cbase + (s & 3) * 64;

    __syncthreads();   // W staged (drains vmcnt)

    for (int t = 0; t < 512; ++t) {
        // ---- stage A = [x_t | h_t] in A-fragment order ----
        const __bf16* hsrc = hbuf + ((size_t)((t & 1) * 32 + gb0)) * 1024;
        for (int m = w * 24; m < w * 24 + 24; ++m) {
            const __bf16* gp;
            if (m < 16) {
                int k = m * 32 + q * 8;
                gp = xb + (((size_t)(gb0 + r) * 512 + t) * 512 + k);
            } else {
                int k = (m - 16) * 32 + q * 8;
                gp = hsrc + r * 1024 + k;
            }
            gload16(gp, A_lds + m * 512);
        }
        __syncthreads();

        // ---- K loop: 48 chained MFMAs, 2 accumulators ----
        f32x4 acc0 = {0.f, 0.f, 0.f, 0.f};
        f32x4 acc1 = {0.f, 0.f, 0.f, 0.f};
#pragma unroll 4
        for (int kk = 0; kk < 48; kk += 2) {
            bf16x8 a0 = *(const bf16x8*)(A_lds + kk * 512 + l * 8);
            bf16x8 b0 = *(const bf16x8*)(W_lds + (kk * 2 + w) * 512 + l * 8);
            acc0 = __builtin_amdgcn_mfma_f32_16x16x32_bf16(a0, b0, acc0, 0, 0, 0);
            bf16x8 a1 = *(const bf16x8*)(A_lds + (kk + 1) * 512 + l * 8);
            bf16x8 b1 = *(const bf16x8*)(W_lds + ((kk + 1) * 2 + w) * 512 + l * 8);
            acc1 = __builtin_amdgcn_mfma_f32_16x16x32_bf16(a1, b1, acc1, 0, 0, 0);
        }

        // ---- regroup gates via per-wave LDS scratch (stride 17 to dodge bank conflicts) ----
        float* sw = scr + w * 272;
#pragma unroll
        for (int rg = 0; rg < 4; ++rg) {
            // C/D layout: col = l&15 (gate col in tile), row = q*4+rg (batch row)
            sw[(l & 15) * 17 + q * 4 + rg] = acc0[rg] + acc1[rg];
        }
        // same-wave lockstep: ds_write then ds_read; compiler inserts lgkmcnt wait
        float xi = sw[(q * 4 + 0) * 17 + r];
        float xf = sw[(q * 4 + 1) * 17 + r];
        float xg = sw[(q * 4 + 2) * 17 + r];
        float xo = sw[(q * 4 + 3) * 17 + r];

        float ii = sigmoidf_(xi + b_i);
        float ff = sigmoidf_(xf + b_f);
        float gg = tanhf_(xg + b_g);
        float oo = sigmoidf_(xo + b_o);
        cst = ff * cst + ii * gg;
        float h = oo * tanhf_(cst);

        const int bglob = gb0 + r;
        out[((size_t)bglob * 512 + t) * 1024 + u] = h;
        hbuf[((size_t)(((t + 1) & 1) * 32 + bglob)) * 1024 + u] = (__bf16)h;

        if (t < 511) {
            __threadfence();     // release: h writes visible agent-wide
            __syncthreads();     // both waves' stores fenced before arrival
            if (tid == 0) {
                __hip_atomic_fetch_add(mycnt, 1u, __ATOMIC_RELAXED, __HIP_MEMORY_SCOPE_AGENT);
                const unsigned target = 128u * (unsigned)(t + 1);
                for (;;) {
                    unsigned sum = 0;
#pragma unroll
                    for (int i = 0; i < 4; ++i)
                        sum += __hip_atomic_load(cbase + i * 64, __ATOMIC_RELAXED,
                                                 __HIP_MEMORY_SCOPE_AGENT);
                    if (sum >= target) break;
                }
                __builtin_amdgcn_fence(__ATOMIC_ACQUIRE, "agent");  // invalidate L1
            }
            __syncthreads();
        }
    }
}

extern "C" void kernel_launch(void* const* d_in, const int* in_sizes, int n_in,
                              void* d_out, int out_size, void* d_ws, size_t ws_size,
                              hipStream_t stream) {
    const float* data = (const float*)d_in[0];   // [32,512,512]
    const float* Wx   = (const float*)d_in[1];   // [512,4096]
    const float* Wh   = (const float*)d_in[2];   // [1024,4096]
    const float* b    = (const float*)d_in[3];   // [4096]
    float* out = (float*)d_out;                  // [32,512,1024]

    if (ws_size < (size_t)WS_NEEDED) return;     // need ~29.5 MB scratch

    char* ws = (char*)d_ws;
    __bf16*   wfrag = (__bf16*)(ws + WS_WFRAG);
    __bf16*   xbuf  = (__bf16*)(ws + WS_XB);
    __bf16*   hbuf  = (__bf16*)(ws + WS_HBUF);
    unsigned* cnt   = (unsigned*)(ws + WS_CNT);

    // allow >64KB dynamic LDS (149,632 B) — host-side attribute, graph-capture safe
    hipFuncSetAttribute((const void*)lstm_main,
                        hipFuncAttributeMaxDynamicSharedMemorySize, LDS_BYTES);

    prep_w_kernel<<<3072, 256, 0, stream>>>(Wx, Wh, wfrag);
    prep_x_kernel<<<8192, 256, 0, stream>>>(data, xbuf);
    hipMemsetAsync(hbuf, 0, 131072 + 2048, stream);   // h0 = 0, counters = 0
    lstm_main<<<256, 128, LDS_BYTES, stream>>>(xbuf, wfrag, b, out, hbuf, cnt);
}

// Round 2
// 2704.342 us; speedup vs baseline: 3.8395x; 3.8395x over previous
//
#include <hip/hip_runtime.h>
#include <cstdint>
#include <cstddef>

typedef __bf16 bf16x8 __attribute__((ext_vector_type(8)));
typedef __bf16 bf16x4 __attribute__((ext_vector_type(4)));
typedef float  f32x4  __attribute__((ext_vector_type(4)));

// ---------------- ws layout (bytes) ----------------
#define WS_WFRAG   0
#define WS_XB      12582912
#define WS_HBUF    29360128
#define WS_CNT     29491200
#define WS_NEEDED  29493248

// LDS: A 49152 ; W 98304 ; scr 2176 ; hpack 256  = 149888
#define LDS_BYTES  149888

__device__ __forceinline__ void gload16(const void* g, void* l) {
    __builtin_amdgcn_global_load_lds(
        (const __attribute__((address_space(1))) void*)(g),
        (__attribute__((address_space(3))) void*)(l),
        16, 0, 0);
}

__device__ __forceinline__ float sigmoidf_(float x) {
    return 1.f / (1.f + __expf(-x));
}
__device__ __forceinline__ float tanhf_(float x) {
    x = fminf(fmaxf(x, -15.f), 15.f);
    float e2 = __expf(2.f * x);
    return (e2 - 1.f) / (e2 + 1.f);
}

// ---- prep: shuffle fused W = [Wx ; Wh] into bf16 B-fragment order ----
__global__ void __launch_bounds__(256) prep_w_kernel(const float* __restrict__ Wx,
                                                     const float* __restrict__ Wh,
                                                     __bf16* __restrict__ wfrag) {
    int tid = blockIdx.x * 256 + threadIdx.x;   // 0 .. 786431
    int l   = tid & 63;
    int m   = tid >> 6;
    int nt  = m & 1;
    int sk  = m >> 1;
    int kk  = sk % 48;
    int s   = sk / 48;
    int lc  = l & 15;
    int c   = nt * 16 + lc;
    int uu  = c >> 2;
    int gi  = c & 3;
    int n   = gi * 1024 + s * 8 + uu;
    int k0  = kk * 32 + (l >> 4) * 8;
    bf16x8 v;
#pragma unroll
    for (int j = 0; j < 8; ++j) {
        int k  = k0 + j;
        float f = (k < 512) ? Wx[k * 4096 + n] : Wh[(k - 512) * 4096 + n];
        v[j] = (__bf16)f;
    }
    ((bf16x8*)wfrag)[tid] = v;
}

// ---- prep: cast data fp32 -> bf16 ----
__global__ void __launch_bounds__(256) prep_x_kernel(const float* __restrict__ data,
                                                     __bf16* __restrict__ xb) {
    int tid = blockIdx.x * 256 + threadIdx.x;
    float4 v = ((const float4*)data)[tid];
    bf16x4 o;
    o[0] = (__bf16)v.x; o[1] = (__bf16)v.y; o[2] = (__bf16)v.z; o[3] = (__bf16)v.w;
    ((bf16x4*)xb)[tid] = o;
}

// ---- persistent LSTM kernel ----
// grid = 256 blocks x 128 threads. block -> (g = bid>>7, s = bid&127).
// All cross-block traffic (h, counters) via agent-scope atomics (cache-bypass,
// coherent at IF point) -> NO fences, NO per-step L2 writeback/invalidate.
__global__ void __launch_bounds__(128)
lstm_main(const __bf16* __restrict__ xb, const __bf16* __restrict__ wfrag,
          const float* __restrict__ bias, float* __restrict__ out,
          __bf16* __restrict__ hbuf, unsigned* __restrict__ cnt) {
    extern __shared__ char smem[];
    __bf16* A_lds = (__bf16*)smem;                        // 48 chunks * 512 bf16
    __bf16* W_lds = (__bf16*)(smem + 49152);              // 96 chunks * 512 bf16
    float*  scr   = (float*)(smem + 49152 + 98304);       // 2 * 272 f32
    __bf16* hpack = (__bf16*)(smem + 49152 + 98304 + 2176); // 16 rows * 8 units

    const int tid = threadIdx.x;
    const int l   = tid & 63;
    const int w   = tid >> 6;        // wave id == N-tile id (0,1)
    const int q   = l >> 4;
    const int r   = l & 15;
    const int bid = blockIdx.x;
    const int s   = bid & 127;
    const int g   = bid >> 7;
    const int gb0 = g * 16;

    // ---- stage W slice into LDS (once), cached path ----
    const __bf16* wsrc = wfrag + (size_t)s * 49152;
    for (int m = w * 48; m < w * 48 + 48; ++m) {
        gload16(wsrc + m * 512 + l * 8, W_lds + m * 512);
    }

    const int uu = w * 4 + q;
    const int u  = s * 8 + uu;
    const float b_i = bias[u];
    const float b_f = bias[1024 + u];
    const float b_g = bias[2048 + u];
    const float b_o = bias[3072 + u];
    float cst = 0.f;

    unsigned* cbase = cnt + g * 256;
    unsigned* mycnt = cbase + (s & 3) * 64;

    __syncthreads();   // W staged (drains vmcnt)

    for (int t = 0; t < 512; ++t) {
        // ---- stage x_t chunks (cached, stays hot in L2) ----
#pragma unroll
        for (int j = 0; j < 8; ++j) {
            int m = w * 8 + j;
            int k = m * 32 + q * 8;
            gload16(xb + (((size_t)(gb0 + r) * 512 + t) * 512 + k), A_lds + m * 512);
        }
        // ---- stage h chunks via agent-scope atomic loads (coherent, no fence) ----
        const __bf16* hsrc = hbuf + (size_t)((t & 1) * 32 + gb0) * 1024;
        unsigned long long va[16], vb[16];
#pragma unroll
        for (int j = 0; j < 16; ++j) {
            int kh = (w * 16 + j) * 32 + q * 8;
            const unsigned long long* p =
                (const unsigned long long*)(hsrc + (size_t)r * 1024 + kh);
            va[j] = __hip_atomic_load(p,     __ATOMIC_RELAXED, __HIP_MEMORY_SCOPE_AGENT);
            vb[j] = __hip_atomic_load(p + 1, __ATOMIC_RELAXED, __HIP_MEMORY_SCOPE_AGENT);
        }
#pragma unroll
        for (int j = 0; j < 16; ++j) {
            int m = 16 + w * 16 + j;
            unsigned long long tmp[2] = {va[j], vb[j]};
            *((ulonglong2*)(A_lds + m * 512 + l * 8)) = *(const ulonglong2*)tmp;
        }
        __syncthreads();

        // ---- K loop: 48 chained MFMAs, 2 accumulators ----
        f32x4 acc0 = {0.f, 0.f, 0.f, 0.f};
        f32x4 acc1 = {0.f, 0.f, 0.f, 0.f};
#pragma unroll 4
        for (int kk = 0; kk < 48; kk += 2) {
            bf16x8 a0 = *(const bf16x8*)(A_lds + kk * 512 + l * 8);
            bf16x8 b0 = *(const bf16x8*)(W_lds + (kk * 2 + w) * 512 + l * 8);
            acc0 = __builtin_amdgcn_mfma_f32_16x16x32_bf16(a0, b0, acc0, 0, 0, 0);
            bf16x8 a1 = *(const bf16x8*)(A_lds + (kk + 1) * 512 + l * 8);
            bf16x8 b1 = *(const bf16x8*)(W_lds + ((kk + 1) * 2 + w) * 512 + l * 8);
            acc1 = __builtin_amdgcn_mfma_f32_16x16x32_bf16(a1, b1, acc1, 0, 0, 0);
        }

        // ---- regroup gates via per-wave LDS scratch ----
        float* sw = scr + w * 272;
#pragma unroll
        for (int rg = 0; rg < 4; ++rg) {
            sw[(l & 15) * 17 + q * 4 + rg] = acc0[rg] + acc1[rg];
        }
        float xi = sw[(q * 4 + 0) * 17 + r];
        float xf = sw[(q * 4 + 1) * 17 + r];
        float xg = sw[(q * 4 + 2) * 17 + r];
        float xo = sw[(q * 4 + 3) * 17 + r];

        float ii = sigmoidf_(xi + b_i);
        float ff = sigmoidf_(xf + b_f);
        float gg = tanhf_(xg + b_g);
        float oo = sigmoidf_(xo + b_o);
        cst = ff * cst + ii * gg;
        float h = oo * tanhf_(cst);

        const int bglob = gb0 + r;
        out[((size_t)bglob * 512 + t) * 1024 + u] = h;   // cached store, flushed at kernel end
        hpack[r * 8 + uu] = (__bf16)h;                   // pack for 8-B atomic stores

        if (t < 511) {
            __syncthreads();   // hpack ready
            // 32 threads publish h via 8-B agent-scope atomic stores (no fence)
            if (tid < 32) {
                int row  = tid >> 1;
                int half = tid & 1;
                unsigned long long v = ((const unsigned long long*)hpack)[tid];
                unsigned long long* dst = (unsigned long long*)
                    (hbuf + (size_t)(((t + 1) & 1) * 32 + gb0 + row) * 1024 + s * 8) + half;
                __hip_atomic_store(dst, v, __ATOMIC_RELAXED, __HIP_MEMORY_SCOPE_AGENT);
            }
            __syncthreads();   // drains each thread's vmcnt -> h stores at coherent point
            if (tid == 0) {
                __hip_atomic_fetch_add(mycnt, 1u, __ATOMIC_RELAXED, __HIP_MEMORY_SCOPE_AGENT);
                const unsigned target = 128u * (unsigned)(t + 1);
                for (;;) {
                    unsigned sum = 0;
#pragma unroll
                    for (int i = 0; i < 4; ++i)
                        sum += __hip_atomic_load(cbase + i * 64, __ATOMIC_RELAXED,
                                                 __HIP_MEMORY_SCOPE_AGENT);
                    if (sum >= target) break;
                }
            }
            __syncthreads();
        } else {
            // last step: h not needed further; just finish
        }
    }
}

extern "C" void kernel_launch(void* const* d_in, const int* in_sizes, int n_in,
                              void* d_out, int out_size, void* d_ws, size_t ws_size,
                              hipStream_t stream) {
    const float* data = (const float*)d_in[0];
    const float* Wx   = (const float*)d_in[1];
    const float* Wh   = (const float*)d_in[2];
    const float* b    = (const float*)d_in[3];
    float* out = (float*)d_out;

    if (ws_size < (size_t)WS_NEEDED) return;

    char* ws = (char*)d_ws;
    __bf16*   wfrag = (__bf16*)(ws + WS_WFRAG);
    __bf16*   xbuf  = (__bf16*)(ws + WS_XB);
    __bf16*   hbuf  = (__bf16*)(ws + WS_HBUF);
    unsigned* cnt   = (unsigned*)(ws + WS_CNT);

    hipFuncSetAttribute((const void*)lstm_main,
                        hipFuncAttributeMaxDynamicSharedMemorySize, LDS_BYTES);

    prep_w_kernel<<<3072, 256, 0, stream>>>(Wx, Wh, wfrag);
    prep_x_kernel<<<8192, 256, 0, stream>>>(data, xbuf);
    hipMemsetAsync(hbuf, 0, 131072 + 2048, stream);   // h0 = 0, counters = 0
    lstm_main<<<256, 128, LDS_BYTES, stream>>>(xbuf, wfrag, b, out, hbuf, cnt);
}

// Round 3
// 2449.516 us; speedup vs baseline: 4.2389x; 1.1040x over previous
//
#include <hip/hip_runtime.h>
#include <cstdint>
#include <cstddef>

typedef __bf16 bf16x8 __attribute__((ext_vector_type(8)));
typedef __bf16 bf16x4 __attribute__((ext_vector_type(4)));
typedef float  f32x4  __attribute__((ext_vector_type(4)));

// ---------------- ws layout (bytes) ----------------
#define WS_WFRAG   0
#define WS_XB      12582912
#define WS_HBUF    29360128
#define WS_CNT     29491200
#define WS_NEEDED  29495296

// LDS layout (bytes): X0 @0 (16384) | X1 @16384 (16384) | H @32768 (32768) | W @65536 (98304)
// total = 163840 (exactly 160 KiB). Epilogue scratch + hpack overlay the DEAD x buffer.
#define LDS_BYTES  163840

__device__ __forceinline__ void gload16(const void* g, void* l) {
    __builtin_amdgcn_global_load_lds(
        (const __attribute__((address_space(1))) void*)(g),
        (__attribute__((address_space(3))) void*)(l),
        16, 0, 0);
}

__device__ __forceinline__ float sigmoidf_(float x) {
    return 1.f / (1.f + __expf(-x));
}
__device__ __forceinline__ float tanhf_(float x) {
    x = fminf(fmaxf(x, -15.f), 15.f);
    float e2 = __expf(2.f * x);
    return (e2 - 1.f) / (e2 + 1.f);
}

// ---- prep: shuffle fused W = [Wx ; Wh] into bf16 B-fragment order ----
__global__ void __launch_bounds__(256) prep_w_kernel(const float* __restrict__ Wx,
                                                     const float* __restrict__ Wh,
                                                     __bf16* __restrict__ wfrag) {
    int tid = blockIdx.x * 256 + threadIdx.x;   // 0 .. 786431
    int l   = tid & 63;
    int m   = tid >> 6;
    int nt  = m & 1;
    int sk  = m >> 1;
    int kk  = sk % 48;
    int s   = sk / 48;
    int lc  = l & 15;
    int c   = nt * 16 + lc;
    int uu  = c >> 2;
    int gi  = c & 3;
    int n   = gi * 1024 + s * 8 + uu;
    int k0  = kk * 32 + (l >> 4) * 8;
    bf16x8 v;
#pragma unroll
    for (int j = 0; j < 8; ++j) {
        int k  = k0 + j;
        float f = (k < 512) ? Wx[k * 4096 + n] : Wh[(k - 512) * 4096 + n];
        v[j] = (__bf16)f;
    }
    ((bf16x8*)wfrag)[tid] = v;
}

// ---- prep: cast data fp32 -> bf16 ----
__global__ void __launch_bounds__(256) prep_x_kernel(const float* __restrict__ data,
                                                     __bf16* __restrict__ xb) {
    int tid = blockIdx.x * 256 + threadIdx.x;
    float4 v = ((const float4*)data)[tid];
    bf16x4 o;
    o[0] = (__bf16)v.x; o[1] = (__bf16)v.y; o[2] = (__bf16)v.z; o[3] = (__bf16)v.w;
    ((bf16x4*)xb)[tid] = o;
}

// ---- persistent LSTM kernel ----
// grid = 256 blocks x 128 threads. block -> (g = bid>>7, s = bid&127).
// Cross-block traffic via agent-scope atomics (no fences). x double-buffered in
// LDS; x_{t+1} prefetched during the barrier poll window.
__global__ void __launch_bounds__(128)
lstm_main(const __bf16* __restrict__ xb, const __bf16* __restrict__ wfrag,
          const float* __restrict__ bias, float* __restrict__ out,
          __bf16* __restrict__ hbuf, unsigned* __restrict__ cnt) {
    extern __shared__ char smem[];
    __bf16* X_lds = (__bf16*)smem;                 // 2 buffers * 16 chunks * 512 bf16
    __bf16* H_lds = (__bf16*)(smem + 32768);       // 32 chunks * 512 bf16
    __bf16* W_lds = (__bf16*)(smem + 65536);       // 96 chunks * 512 bf16

    const int tid = threadIdx.x;
    const int l   = tid & 63;
    const int w   = tid >> 6;        // wave id == N-tile id (0,1)
    const int q   = l >> 4;
    const int r   = l & 15;
    const int bid = blockIdx.x;
    const int s   = bid & 127;
    const int g   = bid >> 7;
    const int gb0 = g * 16;

    // ---- stage W slice into LDS (once) ----
    const __bf16* wsrc = wfrag + (size_t)s * 49152;
    for (int m = w * 48; m < w * 48 + 48; ++m) {
        gload16(wsrc + m * 512 + l * 8, W_lds + m * 512);
    }

    const int uu = w * 4 + q;
    const int u  = s * 8 + uu;
    const float b_i = bias[u];
    const float b_f = bias[1024 + u];
    const float b_g = bias[2048 + u];
    const float b_o = bias[3072 + u];
    float cst = 0.f;

    unsigned* cbase = cnt + g * 512;             // 8 lines * 64 uints
    unsigned* mycnt = cbase + (s & 7) * 64;

    // ---- prefetch x_0 into X buffer 0 ----
    {
        const __bf16* xrow = xb + (size_t)(gb0 + r) * 512 * 512;
#pragma unroll
        for (int j = 0; j < 8; ++j) {
            int m = w * 8 + j;
            gload16(xrow + m * 32 + q * 8, X_lds + m * 512);
        }
    }

    __syncthreads();   // W + x_0 staged (drains vmcnt)

    for (int t = 0; t < 512; ++t) {
        // ---- stage h_t via agent-scope atomic loads (coherent, no fence) ----
        const __bf16* hsrc = hbuf + (size_t)((t & 1) * 32 + gb0) * 1024;
        unsigned long long va[16], vb[16];
#pragma unroll
        for (int j = 0; j < 16; ++j) {
            int kh = (w * 16 + j) * 32 + q * 8;
            const unsigned long long* p =
                (const unsigned long long*)(hsrc + (size_t)r * 1024 + kh);
            va[j] = __hip_atomic_load(p,     __ATOMIC_RELAXED, __HIP_MEMORY_SCOPE_AGENT);
            vb[j] = __hip_atomic_load(p + 1, __ATOMIC_RELAXED, __HIP_MEMORY_SCOPE_AGENT);
        }
#pragma unroll
        for (int j = 0; j < 16; ++j) {
            int m = w * 16 + j;
            unsigned long long tmp[2] = {va[j], vb[j]};
            *((ulonglong2*)(H_lds + m * 512 + l * 8)) = *(const ulonglong2*)tmp;
        }
        __syncthreads();   // h staged; also x_t prefetch already drained last iter

        // ---- K loop: 48 chained MFMAs, 2 accumulators ----
        const __bf16* Xc = X_lds + (t & 1) * 8192;
        f32x4 acc0 = {0.f, 0.f, 0.f, 0.f};
        f32x4 acc1 = {0.f, 0.f, 0.f, 0.f};
#pragma unroll 4
        for (int kk = 0; kk < 48; kk += 2) {
            const __bf16* a0p = (kk < 16)     ? (Xc + kk * 512)       : (H_lds + (kk - 16) * 512);
            const __bf16* a1p = (kk + 1 < 16) ? (Xc + (kk + 1) * 512) : (H_lds + (kk - 15) * 512);
            bf16x8 a0 = *(const bf16x8*)(a0p + l * 8);
            bf16x8 b0 = *(const bf16x8*)(W_lds + (kk * 2 + w) * 512 + l * 8);
            acc0 = __builtin_amdgcn_mfma_f32_16x16x32_bf16(a0, b0, acc0, 0, 0, 0);
            bf16x8 a1 = *(const bf16x8*)(a1p + l * 8);
            bf16x8 b1 = *(const bf16x8*)(W_lds + ((kk + 1) * 2 + w) * 512 + l * 8);
            acc1 = __builtin_amdgcn_mfma_f32_16x16x32_bf16(a1, b1, acc1, 0, 0, 0);
        }

        // ---- regroup gates via scratch overlaid on the DEAD x buffer ----
        // X[(t+1)&1] holds x_{t-1} (dead); it is re-filled only by the prefetch
        // issued later this iteration, after scratch+hpack are consumed.
        float*  scr   = (float*)(smem + ((t + 1) & 1) * 16384);
        __bf16* hpack = (__bf16*)(smem + ((t + 1) & 1) * 16384 + 2176);
        float* sw = scr + w * 272;
#pragma unroll
        for (int rg = 0; rg < 4; ++rg) {
            sw[(l & 15) * 17 + q * 4 + rg] = acc0[rg] + acc1[rg];
        }
        float xi = sw[(q * 4 + 0) * 17 + r];
        float xf = sw[(q * 4 + 1) * 17 + r];
        float xg = sw[(q * 4 + 2) * 17 + r];
        float xo = sw[(q * 4 + 3) * 17 + r];

        float ii = sigmoidf_(xi + b_i);
        float ff = sigmoidf_(xf + b_f);
        float gg = tanhf_(xg + b_g);
        float oo = sigmoidf_(xo + b_o);
        cst = ff * cst + ii * gg;
        float h = oo * tanhf_(cst);

        const int bglob = gb0 + r;

        if (t < 511) {
            hpack[r * 8 + uu] = (__bf16)h;
            __syncthreads();   // hpack ready (both waves done with MFMA/scratch)
            if (tid < 32) {
                int row  = tid >> 1;
                int half = tid & 1;
                unsigned long long v = ((const unsigned long long*)hpack)[tid];
                unsigned long long* dst = (unsigned long long*)
                    (hbuf + (size_t)(((t + 1) & 1) * 32 + gb0 + row) * 1024 + s * 8) + half;
                __hip_atomic_store(dst, v, __ATOMIC_RELAXED, __HIP_MEMORY_SCOPE_AGENT);
            }
            __syncthreads();   // drains vmcnt -> h stores at coherent point
            if (tid == 0) {
                __hip_atomic_fetch_add(mycnt, 1u, __ATOMIC_RELAXED, __HIP_MEMORY_SCOPE_AGENT);
            }
            // ---- off-critical-path work overlapping the poll ----
            out[((size_t)bglob * 512 + t) * 1024 + u] = h;
            {   // prefetch x_{t+1} into X[(t+1)&1] (clobbers scr/hpack — both dead)
                const __bf16* xrow = xb + ((size_t)(gb0 + r) * 512 + (t + 1)) * 512;
                __bf16* Xn = X_lds + ((t + 1) & 1) * 8192;
#pragma unroll
                for (int j = 0; j < 8; ++j) {
                    int m = w * 8 + j;
                    gload16(xrow + m * 32 + q * 8, Xn + m * 512);
                }
            }
            if (tid == 0) {
                const unsigned target = 128u * (unsigned)(t + 1);
                for (;;) {
                    unsigned sum = 0;
#pragma unroll
                    for (int i = 0; i < 8; ++i)
                        sum += __hip_atomic_load(cbase + i * 64, __ATOMIC_RELAXED,
                                                 __HIP_MEMORY_SCOPE_AGENT);
                    if (sum >= target) break;
                }
            }
            __syncthreads();   // release; drains out store + x prefetch
        } else {
            out[((size_t)bglob * 512 + t) * 1024 + u] = h;
        }
    }
}

extern "C" void kernel_launch(void* const* d_in, const int* in_sizes, int n_in,
                              void* d_out, int out_size, void* d_ws, size_t ws_size,
                              hipStream_t stream) {
    const float* data = (const float*)d_in[0];
    const float* Wx   = (const float*)d_in[1];
    const float* Wh   = (const float*)d_in[2];
    const float* b    = (const float*)d_in[3];
    float* out = (float*)d_out;

    if (ws_size < (size_t)WS_NEEDED) return;

    char* ws = (char*)d_ws;
    __bf16*   wfrag = (__bf16*)(ws + WS_WFRAG);
    __bf16*   xbuf  = (__bf16*)(ws + WS_XB);
    __bf16*   hbuf  = (__bf16*)(ws + WS_HBUF);
    unsigned* cnt   = (unsigned*)(ws + WS_CNT);

    hipFuncSetAttribute((const void*)lstm_main,
                        hipFuncAttributeMaxDynamicSharedMemorySize, LDS_BYTES);

    prep_w_kernel<<<3072, 256, 0, stream>>>(Wx, Wh, wfrag);
    prep_x_kernel<<<8192, 256, 0, stream>>>(data, xbuf);
    hipMemsetAsync(hbuf, 0, 131072 + 4096, stream);   // h0 = 0, counters = 0
    lstm_main<<<256, 128, LDS_BYTES, stream>>>(xbuf, wfrag, b, out, hbuf, cnt);
}